// Round 11
// baseline (587.204 us; speedup 1.0000x reference)
//
#include <hip/hip_runtime.h>

#define N 768
#define D 128
#define NSQ (N*N)
#define EPS 1e-5f

typedef __bf16 bf16;
typedef __bf16 bf16x4 __attribute__((ext_vector_type(4)));
typedef __bf16 bf16x8 __attribute__((ext_vector_type(8)));
typedef float f32x4 __attribute__((ext_vector_type(4)));

__device__ __forceinline__ void gld16(const void* g, void* l) {
    __builtin_amdgcn_global_load_lds(
        (const __attribute__((address_space(1))) unsigned int*)g,
        (__attribute__((address_space(3))) unsigned int*)l, 16, 0, 0);
}

// raw barrier: lgkm drain (LDS visibility) WITHOUT the vmcnt(0) store/DMA drain
__device__ __forceinline__ void barrier_lds() {
    asm volatile("s_waitcnt lgkmcnt(0)" ::: "memory");
    __builtin_amdgcn_s_barrier();
    __builtin_amdgcn_sched_barrier(0);
}

// ---------------- K0: convert 6 weight matrices fp32 -> bf16 ----------------
__global__ void k_convert_w(const float* __restrict__ lp, const float* __restrict__ lg,
                            const float* __restrict__ rp, const float* __restrict__ rg,
                            const float* __restrict__ op, const float* __restrict__ og,
                            bf16* __restrict__ dst) {
    const float* srcs[6] = {lp, lg, rp, rg, op, og};
    int m = blockIdx.y;
    int i = blockIdx.x * 256 + threadIdx.x;   // 64 blocks x 256 = 16384
    dst[m * 16384 + i] = (bf16)srcs[m][i];
}

// ---------------- K1v4: fused LN + 4 GEMMs + gates, 1 raw barrier/tile ------
__global__ __launch_bounds__(512, 2) void k_ln_gate2(
    const float* __restrict__ pair, const float* __restrict__ lnw, const float* __restrict__ lnb,
    const bf16* __restrict__ wbf,
    const float* __restrict__ lp_b, const float* __restrict__ lg_b,
    const float* __restrict__ rp_b, const float* __restrict__ rg_b,
    bf16* __restrict__ left_t, bf16* __restrict__ right_t)
{
    __shared__ bf16 zt[2][64 * 128];   // 2 x 16 KB, xor-swizzled 16B chunks

    const int t = threadIdx.x;
    const int lane = t & 63, wid = t >> 6;
    const int side = wid >> 2, dq = wid & 3;
    const int lr = lane & 15, lh = lane >> 4;

    const bf16* wPsrc = wbf + (side ? 2 : 0) * 16384;
    const bf16* wGsrc = wbf + (side ? 3 : 1) * 16384;
    const float* bPp = side ? rp_b : lp_b;
    const float* bGp = side ? rg_b : lg_b;
    bf16* dst = side ? right_t : left_t;

    bf16x8 aP[4][2], aG[4][2];
    #pragma unroll
    for (int kk = 0; kk < 4; ++kk)
        #pragma unroll
        for (int m = 0; m < 2; ++m) {
            int rd = dq * 32 + m * 16 + lr;
            aP[kk][m] = *(const bf16x8*)(wPsrc + rd * 128 + (kk * 4 + lh) * 8);
            aG[kk][m] = *(const bf16x8*)(wGsrc + rd * 128 + (kk * 4 + lh) * 8);
        }
    float bP[2], bG[2];
    #pragma unroll
    for (int m = 0; m < 2; ++m) {
        bP[m] = bPp[dq * 32 + m * 16 + lr];
        bG[m] = bGp[dq * 32 + m * 16 + lr];
    }

    const int r8 = t >> 3, q = t & 7;

    f32x4 lw0 = *(const f32x4*)(lnw + q * 16);
    f32x4 lw1 = *(const f32x4*)(lnw + q * 16 + 4);
    f32x4 lw2 = *(const f32x4*)(lnw + q * 16 + 8);
    f32x4 lw3 = *(const f32x4*)(lnw + q * 16 + 12);
    f32x4 lb0 = *(const f32x4*)(lnb + q * 16);
    f32x4 lb1 = *(const f32x4*)(lnb + q * 16 + 4);
    f32x4 lb2 = *(const f32x4*)(lnb + q * 16 + 8);
    f32x4 lb3 = *(const f32x4*)(lnb + q * 16 + 12);

    const int bid = blockIdx.x, gstride = gridDim.x;

    f32x4 p0, p1, p2, p3;
    {
        const float* prow = pair + (size_t)(bid * 64 + r8) * 128 + q * 16;
        p0 = *(const f32x4*)(prow);
        p1 = *(const f32x4*)(prow + 4);
        p2 = *(const f32x4*)(prow + 8);
        p3 = *(const f32x4*)(prow + 12);
    }

    int buf = 0;
    for (int tile = bid; tile < NSQ / 64; tile += gstride) {
        const int row0 = tile * 64;

        float x[16];
        #pragma unroll
        for (int e = 0; e < 4; ++e) {
            x[e] = p0[e]; x[4 + e] = p1[e]; x[8 + e] = p2[e]; x[12 + e] = p3[e];
        }
        float s1 = 0.f, s2 = 0.f;
        #pragma unroll
        for (int j = 0; j < 16; ++j) { s1 += x[j]; s2 += x[j] * x[j]; }
        s1 += __shfl_xor(s1, 1); s2 += __shfl_xor(s2, 1);
        s1 += __shfl_xor(s1, 2); s2 += __shfl_xor(s2, 2);
        s1 += __shfl_xor(s1, 4); s2 += __shfl_xor(s2, 4);
        float mean = s1 * (1.f / 128.f);
        float rstd = rsqrtf(s2 * (1.f / 128.f) - mean * mean + EPS);

        bf16x8 pk0, pk1;
        #pragma unroll
        for (int e = 0; e < 4; ++e) {
            pk0[e]     = (bf16)((x[e]      - mean) * rstd * lw0[e] + lb0[e]);
            pk0[4 + e] = (bf16)((x[4 + e]  - mean) * rstd * lw1[e] + lb1[e]);
            pk1[e]     = (bf16)((x[8 + e]  - mean) * rstd * lw2[e] + lb2[e]);
            pk1[4 + e] = (bf16)((x[12 + e] - mean) * rstd * lw3[e] + lb3[e]);
        }
        {
            char* zb = (char*)&zt[buf][0];
            *(bf16x8*)(zb + r8 * 256 + ((q * 2)     ^ (r8 & 7)) * 16) = pk0;
            *(bf16x8*)(zb + r8 * 256 + ((q * 2 + 1) ^ (r8 & 7)) * 16) = pk1;
        }
        barrier_lds();   // zt[buf] visible; zt[buf^1] readers (tile-1) all done

        int nt = tile + gstride;
        if (nt < NSQ / 64) {
            const float* prow = pair + (size_t)(nt * 64 + r8) * 128 + q * 16;
            p0 = *(const f32x4*)(prow);
            p1 = *(const f32x4*)(prow + 4);
            p2 = *(const f32x4*)(prow + 8);
            p3 = *(const f32x4*)(prow + 12);
        }

        f32x4 accP[2][4] = {};
        f32x4 accG[2][4] = {};
        const char* zb = (const char*)&zt[buf][0];
        #pragma unroll
        for (int kk = 0; kk < 4; ++kk) {
            bf16x8 bz[4];
            #pragma unroll
            for (int n = 0; n < 4; ++n) {
                int rz = n * 16 + lr;
                bz[n] = *(const bf16x8*)(zb + rz * 256 + (((kk * 4 + lh)) ^ (rz & 7)) * 16);
            }
            #pragma unroll
            for (int m = 0; m < 2; ++m)
                #pragma unroll
                for (int n = 0; n < 4; ++n) {
                    accP[m][n] = __builtin_amdgcn_mfma_f32_16x16x32_bf16(bz[n], aP[kk][m], accP[m][n], 0, 0, 0);
                    accG[m][n] = __builtin_amdgcn_mfma_f32_16x16x32_bf16(bz[n], aG[kk][m], accG[m][n], 0, 0, 0);
                }
        }

        #pragma unroll
        for (int m = 0; m < 2; ++m) {
            const int d = dq * 32 + m * 16 + lr;
            bf16* drow = dst + (size_t)d * NSQ + row0 + lh * 4;
            #pragma unroll
            for (int n = 0; n < 4; ++n) {
                bf16x4 pk;
                #pragma unroll
                for (int reg = 0; reg < 4; ++reg) {
                    float g = accG[m][n][reg] + bG[m];
                    float p = accP[m][n][reg] + bP[m];
                    pk[reg] = (bf16)(p * (1.f / (1.f + __expf(-g))));
                }
                *(bf16x4*)(drow + n * 16) = pk;
            }
        }
        buf ^= 1;
    }
}

// ---------------- K3 (R7 best variant): 128^2 tile, XCD-pinned --------------
__global__ __launch_bounds__(256, 4) void k_tri(
    const bf16* __restrict__ left_t, const bf16* __restrict__ right_t, bf16* __restrict__ tri_t)
{
    __shared__ bf16 at[2][128 * 32];
    __shared__ bf16 bt[2][128 * 32];
    const int t = threadIdx.x;
    const int b = blockIdx.x;
    const int xcd = b & 7;
    const int s = b >> 3;
    const int d = xcd * 16 + s / 36;
    const int tile = s % 36;
    const int ti = tile / 6, tj = tile % 6;
    const bf16* A = left_t + (size_t)d * NSQ;
    const bf16* B = right_t + (size_t)d * NSQ;
    const int i0 = ti * 128, j0 = tj * 128;

    auto stage = [&](int buf, int kt) {
        int k0 = kt * 32;
        #pragma unroll
        for (int c = 0; c < 2; ++c) {
            int sl = c * 256 + t;
            int r = sl >> 2, cp = sl & 3, cl = cp ^ ((r >> 1) & 3);
            gld16(A + (size_t)(i0 + r) * 768 + k0 + cl * 8, (char*)at[buf] + sl * 16);
            gld16(B + (size_t)(j0 + r) * 768 + k0 + cl * 8, (char*)bt[buf] + sl * 16);
        }
    };

    const int lane = t & 63, wid = t >> 6;
    const int wr = wid >> 1, wc = wid & 1;
    const int lr = lane & 15, lh = lane >> 4;

    f32x4 acc[4][4] = {};

    stage(0, 0);
    for (int kt = 0; kt < 24; ++kt) {
        const int buf = kt & 1;
        asm volatile("s_waitcnt vmcnt(0)" ::: "memory");
        __builtin_amdgcn_s_barrier();

        const bf16* ab = at[buf];
        const bf16* bb = bt[buf];
        bf16x8 af[4], bff[4];
        #pragma unroll
        for (int m = 0; m < 4; ++m) {
            int r = wr * 64 + m * 16 + lr;
            int phys = lh ^ ((r >> 1) & 3);
            af[m] = *(const bf16x8*)((const char*)ab + r * 64 + phys * 16);
        }
        #pragma unroll
        for (int n = 0; n < 4; ++n) {
            int r = wc * 64 + n * 16 + lr;
            int phys = lh ^ ((r >> 1) & 3);
            bff[n] = *(const bf16x8*)((const char*)bb + r * 64 + phys * 16);
        }

        if (kt < 23) stage(buf ^ 1, kt + 1);

        #pragma unroll
        for (int m = 0; m < 4; ++m)
            #pragma unroll
            for (int n = 0; n < 4; ++n)
                acc[m][n] = __builtin_amdgcn_mfma_f32_16x16x32_bf16(bff[n], af[m], acc[m][n], 0, 0, 0);
    }

    bf16* C = tri_t + (size_t)d * NSQ;
    #pragma unroll
    for (int m = 0; m < 4; ++m) {
        const int ri = i0 + wr * 64 + m * 16 + lr;
        bf16* crow = C + (size_t)ri * 768 + j0 + wc * 64 + lh * 4;
        #pragma unroll
        for (int n = 0; n < 4; ++n) {
            bf16x4 pk;
            #pragma unroll
            for (int reg = 0; reg < 4; ++reg)
                pk[reg] = (bf16)acc[m][n][reg];
            *(bf16x4*)(crow + n * 16) = pk;
        }
    }
}

// ---------------- K5v6: fused cn-LN + out-gate + residual + final LN --------
// k_cln is GONE: this kernel reads tri_t (d-major) directly, transposes into
// LDS via coalesced u16 loads + swizzled bf16x8 ds_writes, computes the d-LN
// in-place, then the dual GEMM + gate + residual + final LN as before.
__global__ __launch_bounds__(512, 2) void k_final3(
    const float* __restrict__ pair, const bf16* __restrict__ tri_t,
    const bf16* __restrict__ wbf,
    const float* __restrict__ cn_w, const float* __restrict__ cn_b,
    const float* __restrict__ op_b, const float* __restrict__ og_b,
    const float* __restrict__ lnow, const float* __restrict__ lnob,
    float* __restrict__ out)
{
    __shared__ bf16 zt[64 * 128];       // raw pair bf16, swizzled      16 KB
    __shared__ bf16 tt[2][64 * 128];    // tri tile [ij][d-swz], dbuf   32 KB
    __shared__ bf16 ub[64 * 136];       // gated output exchange        17 KB

    const int t = threadIdx.x;
    const int lane = t & 63, wid = t >> 6;
    const int dq = wid & 3, wh = wid >> 2;
    const int lr = lane & 15, lh = lane >> 4;

    const bf16* opsrc = wbf + 4 * 16384;
    const bf16* ogsrc = wbf + 5 * 16384;

    bf16x8 aOG[4][2], aOP[4][2];
    #pragma unroll
    for (int kk = 0; kk < 4; ++kk)
        #pragma unroll
        for (int m = 0; m < 2; ++m) {
            int rd = dq * 32 + m * 16 + lr;
            aOG[kk][m] = *(const bf16x8*)(ogsrc + rd * 128 + (kk * 4 + lh) * 8);
            aOP[kk][m] = *(const bf16x8*)(opsrc + rd * 128 + (kk * 4 + lh) * 8);
        }
    f32x4 vbOG[2], vbOP[2];
    #pragma unroll
    for (int m = 0; m < 2; ++m) {
        vbOG[m] = *(const f32x4*)(og_b + dq * 32 + m * 16 + lh * 4);
        vbOP[m] = *(const f32x4*)(op_b + dq * 32 + m * 16 + lh * 4);
    }

    const int r8 = t >> 3, q = t & 7;
    f32x4 lw0 = *(const f32x4*)(lnow + q * 16);
    f32x4 lw1 = *(const f32x4*)(lnow + q * 16 + 4);
    f32x4 lw2 = *(const f32x4*)(lnow + q * 16 + 8);
    f32x4 lw3 = *(const f32x4*)(lnow + q * 16 + 12);
    f32x4 lb0 = *(const f32x4*)(lnob + q * 16);
    f32x4 lb1 = *(const f32x4*)(lnob + q * 16 + 4);
    f32x4 lb2 = *(const f32x4*)(lnob + q * 16 + 8);
    f32x4 lb3 = *(const f32x4*)(lnob + q * 16 + 12);

    const int ijl = t & 63, g = t >> 6;   // staging geometry
    const int bid = blockIdx.x, gstride = gridDim.x;

    // prologue: stage raw tri tile 0 into tt[0] (loads + swizzled ds_writes)
    {
        const int r0 = bid * 64;
        #pragma unroll
        for (int h = 0; h < 2; ++h) {
            const int do8 = g + 8 * h;
            bf16x8 v;
            #pragma unroll
            for (int e = 0; e < 8; ++e)
                v[e] = tri_t[(size_t)(do8 * 8 + e) * NSQ + r0 + ijl];
            *(bf16x8*)((char*)tt[0] + ijl * 256 + ((do8 ^ (ijl & 7)) * 16)) = v;
        }
    }
    f32x4 pA0, pA1, pA2, pA3;
    {
        const float* prow = pair + (size_t)(bid * 64 + r8) * 128 + q * 16;
        pA0 = *(const f32x4*)(prow);
        pA1 = *(const f32x4*)(prow + 4);
        pA2 = *(const f32x4*)(prow + 8);
        pA3 = *(const f32x4*)(prow + 12);
    }

    int buf = 0;
    for (int tile = bid; tile < NSQ / 64; tile += gstride) {
        const int row0 = tile * 64;

        {   // zt write from pair regs (swizzled)
            bf16x8 pk0, pk1;
            #pragma unroll
            for (int e = 0; e < 4; ++e) {
                pk0[e]     = (bf16)pA0[e];
                pk0[4 + e] = (bf16)pA1[e];
                pk1[e]     = (bf16)pA2[e];
                pk1[4 + e] = (bf16)pA3[e];
            }
            char* zb = (char*)zt;
            *(bf16x8*)(zb + r8 * 256 + ((q * 2)     ^ (r8 & 7)) * 16) = pk0;
            *(bf16x8*)(zb + r8 * 256 + ((q * 2 + 1) ^ (r8 & 7)) * 16) = pk1;
        }
        barrier_lds();   // L1: zt visible; tt[buf] raw writes (prev iter) drained

        const int nt = tile + gstride;
        f32x4 pB0 = pA0, pB1 = pA1, pB2 = pA2, pB3 = pA3;
        if (nt < NSQ / 64) {
            const float* prow = pair + (size_t)(nt * 64 + r8) * 128 + q * 16;
            pB0 = *(const f32x4*)(prow);
            pB1 = *(const f32x4*)(prow + 4);
            pB2 = *(const f32x4*)(prow + 8);
            pB3 = *(const f32x4*)(prow + 12);
        }

        // ---- cn-LayerNorm of tt[buf] in place (stats over d per ij row) ----
        {
            char* tb = (char*)tt[buf];
            const int c0 = (2 * q) ^ (r8 & 7), c1 = (2 * q + 1) ^ (r8 & 7);
            bf16x8 x0 = *(const bf16x8*)(tb + r8 * 256 + c0 * 16);
            bf16x8 x1 = *(const bf16x8*)(tb + r8 * 256 + c1 * 16);
            float f[16];
            float s1 = 0.f, s2 = 0.f;
            #pragma unroll
            for (int e = 0; e < 8; ++e) {
                f[e] = (float)x0[e]; f[8 + e] = (float)x1[e];
            }
            #pragma unroll
            for (int j = 0; j < 16; ++j) { s1 += f[j]; s2 += f[j] * f[j]; }
            s1 += __shfl_xor(s1, 1); s2 += __shfl_xor(s2, 1);
            s1 += __shfl_xor(s1, 2); s2 += __shfl_xor(s2, 2);
            s1 += __shfl_xor(s1, 4); s2 += __shfl_xor(s2, 4);
            float mean = s1 * (1.f / 128.f);
            float rstd = rsqrtf(s2 * (1.f / 128.f) - mean * mean + EPS);
            // cn coeffs: logical d = q*16 .. q*16+15
            f32x4 w00 = *(const f32x4*)(cn_w + q * 16);
            f32x4 w01 = *(const f32x4*)(cn_w + q * 16 + 4);
            f32x4 w10 = *(const f32x4*)(cn_w + q * 16 + 8);
            f32x4 w11 = *(const f32x4*)(cn_w + q * 16 + 12);
            f32x4 b00 = *(const f32x4*)(cn_b + q * 16);
            f32x4 b01 = *(const f32x4*)(cn_b + q * 16 + 4);
            f32x4 b10 = *(const f32x4*)(cn_b + q * 16 + 8);
            f32x4 b11 = *(const f32x4*)(cn_b + q * 16 + 12);
            bf16x8 o0, o1;
            #pragma unroll
            for (int e = 0; e < 4; ++e) {
                o0[e]     = (bf16)((f[e]      - mean) * rstd * w00[e] + b00[e]);
                o0[4 + e] = (bf16)((f[4 + e]  - mean) * rstd * w01[e] + b01[e]);
                o1[e]     = (bf16)((f[8 + e]  - mean) * rstd * w10[e] + b10[e]);
                o1[4 + e] = (bf16)((f[12 + e] - mean) * rstd * w11[e] + b11[e]);
            }
            *(bf16x8*)(tb + r8 * 256 + c0 * 16) = o0;
            *(bf16x8*)(tb + r8 * 256 + c1 * 16) = o1;
        }
        barrier_lds();   // L2: normalized tt[buf] visible

        // ---- next-tile tri loads issued BEFORE MFMA (T14 split) ----
        bf16x8 nv0, nv1;
        if (nt < NSQ / 64) {
            const int r0 = nt * 64;
            #pragma unroll
            for (int e = 0; e < 8; ++e) {
                nv0[e] = tri_t[(size_t)(g * 8 + e) * NSQ + r0 + ijl];
                nv1[e] = tri_t[(size_t)((g + 8) * 8 + e) * NSQ + r0 + ijl];
            }
        }

        // ---- dual GEMM: OG gate from zt (raw pair), OP proj from tt (LN'd tri)
        f32x4 accOG[2][2] = {};
        f32x4 accOP[2][2] = {};
        const char* zb = (const char*)zt;
        const char* tb = (const char*)tt[buf];
        #pragma unroll
        for (int kk = 0; kk < 4; ++kk) {
            bf16x8 bzp[2], bzt[2];
            #pragma unroll
            for (int n = 0; n < 2; ++n) {
                int rz = wh * 32 + n * 16 + lr;
                int phys = (kk * 4 + lh) ^ (rz & 7);
                bzp[n] = *(const bf16x8*)(zb + rz * 256 + phys * 16);
                bzt[n] = *(const bf16x8*)(tb + rz * 256 + phys * 16);
            }
            #pragma unroll
            for (int m = 0; m < 2; ++m)
                #pragma unroll
                for (int n = 0; n < 2; ++n) {
                    accOG[m][n] = __builtin_amdgcn_mfma_f32_16x16x32_bf16(aOG[kk][m], bzp[n], accOG[m][n], 0, 0, 0);
                    accOP[m][n] = __builtin_amdgcn_mfma_f32_16x16x32_bf16(aOP[kk][m], bzt[n], accOP[m][n], 0, 0, 0);
                }
        }

        // ---- write next-tile raw chunks (loads have had the GEMM to land) ----
        if (nt < NSQ / 64) {
            *(bf16x8*)((char*)tt[buf ^ 1] + ijl * 256 + ((g       ^ (ijl & 7)) * 16)) = nv0;
            *(bf16x8*)((char*)tt[buf ^ 1] + ijl * 256 + (((g + 8) ^ (ijl & 7)) * 16)) = nv1;
        }

        #pragma unroll
        for (int m = 0; m < 2; ++m)
            #pragma unroll
            for (int n = 0; n < 2; ++n) {
                int rr = wh * 32 + n * 16 + lr;
                bf16x4 v;
                #pragma unroll
                for (int reg = 0; reg < 4; ++reg) {
                    float gg = accOG[m][n][reg] + vbOG[m][reg];
                    float p  = accOP[m][n][reg] + vbOP[m][reg];
                    v[reg] = (bf16)(p * (1.f / (1.f + __expf(-gg))));
                }
                *(bf16x4*)(ub + rr * 136 + dq * 32 + m * 16 + lh * 4) = v;
            }
        barrier_lds();   // L3: ub + next raw tile visible; no vmcnt drain

        {
            float x[16];
            const bf16* ur = ub + r8 * 136 + q * 16;
            bf16x8 u0 = *(const bf16x8*)(ur);
            bf16x8 u1 = *(const bf16x8*)(ur + 8);
            #pragma unroll
            for (int e = 0; e < 4; ++e) {
                x[e]      = pA0[e] + (float)u0[e];
                x[4 + e]  = pA1[e] + (float)u0[4 + e];
                x[8 + e]  = pA2[e] + (float)u1[e];
                x[12 + e] = pA3[e] + (float)u1[4 + e];
            }
            float s1 = 0.f, s2 = 0.f;
            #pragma unroll
            for (int j = 0; j < 16; ++j) { s1 += x[j]; s2 += x[j] * x[j]; }
            s1 += __shfl_xor(s1, 1); s2 += __shfl_xor(s2, 1);
            s1 += __shfl_xor(s1, 2); s2 += __shfl_xor(s2, 2);
            s1 += __shfl_xor(s1, 4); s2 += __shfl_xor(s2, 4);
            float mean = s1 * (1.f / 128.f);
            float rstd = rsqrtf(s2 * (1.f / 128.f) - mean * mean + EPS);
            float* orow = out + (size_t)(row0 + r8) * 128 + q * 16;
            f32x4 o0, o1, o2, o3;
            #pragma unroll
            for (int e = 0; e < 4; ++e) {
                o0[e] = (x[e]      - mean) * rstd * lw0[e] + lb0[e];
                o1[e] = (x[4 + e]  - mean) * rstd * lw1[e] + lb1[e];
                o2[e] = (x[8 + e]  - mean) * rstd * lw2[e] + lb2[e];
                o3[e] = (x[12 + e] - mean) * rstd * lw3[e] + lb3[e];
            }
            *(f32x4*)(orow)      = o0;
            *(f32x4*)(orow + 4)  = o1;
            *(f32x4*)(orow + 8)  = o2;
            *(f32x4*)(orow + 12) = o3;
        }

        pA0 = pB0; pA1 = pB1; pA2 = pB2; pA3 = pB3;
        buf ^= 1;
    }
}

extern "C" void kernel_launch(void* const* d_in, const int* in_sizes, int n_in,
                              void* d_out, int out_size, void* d_ws, size_t ws_size,
                              hipStream_t stream) {
    const float* pair    = (const float*)d_in[0];
    const float* ln_in_w = (const float*)d_in[1];
    const float* ln_in_b = (const float*)d_in[2];
    const float* lp_w    = (const float*)d_in[3];
    const float* lp_b    = (const float*)d_in[4];
    const float* lg_w    = (const float*)d_in[5];
    const float* lg_b    = (const float*)d_in[6];
    const float* rp_w    = (const float*)d_in[7];
    const float* rp_b    = (const float*)d_in[8];
    const float* rg_w    = (const float*)d_in[9];
    const float* rg_b    = (const float*)d_in[10];
    const float* cn_w    = (const float*)d_in[11];
    const float* cn_b    = (const float*)d_in[12];
    const float* op_w    = (const float*)d_in[13];
    const float* op_b    = (const float*)d_in[14];
    const float* og_w    = (const float*)d_in[15];
    const float* og_b    = (const float*)d_in[16];
    const float* ln_out_w = (const float*)d_in[17];
    const float* ln_out_b = (const float*)d_in[18];

    // Buffer plan (no ws growth): left_t/right_t in d_out halves (dead after
    // k_tri; clobbered by the final out-write), tri_t in ws after wbf.
    const size_t HALF = (size_t)128 * NSQ * 2;   // 150,994,944 B
    char* ws = (char*)d_ws;
    bf16* wbf     = (bf16*)ws;
    bf16* tri_t   = (bf16*)(ws + 196608);
    bf16* left_t  = (bf16*)d_out;
    bf16* right_t = (bf16*)((char*)d_out + HALF);

    k_convert_w<<<dim3(64, 6), 256, 0, stream>>>(lp_w, lg_w, rp_w, rg_w, op_w, og_w, wbf);
    k_ln_gate2<<<dim3(512), 512, 0, stream>>>(pair, ln_in_w, ln_in_b, wbf,
                                              lp_b, lg_b, rp_b, rg_b, left_t, right_t);
    k_tri<<<dim3(4608), 256, 0, stream>>>(left_t, right_t, tri_t);
    k_final3<<<dim3(512), 512, 0, stream>>>(pair, tri_t, wbf, cn_w, cn_b,
                                            op_b, og_b, ln_out_w, ln_out_b, (float*)d_out);
}